// Round 4
// baseline (1587.931 us; speedup 1.0000x reference)
//
#include <hip/hip_runtime.h>
#include <hip/hip_bf16.h>

// ---------------------------------------------------------------------------
// EncoderGAE: 8-layer GCN encoder on MI355X.
// R4: (1) prologue: one u64 atomic per edge carries deg-sum (fix24) + rank;
//         fill becomes atomic-free with a single int2 write per edge.
//     (2) BN-apply + leakyReLU fused into GEMM A-staging (full-width 128x256
//         tile, A read once, fp32 in / bf16 frags out). bn_apply removed.
//     (3) bn_stats: float4 + 64-row blocks + LDS pre-reduce.
// ---------------------------------------------------------------------------

#define NN 50000
#define NE 800000
#define DD 256

typedef __attribute__((ext_vector_type(8))) short short8;
typedef __attribute__((ext_vector_type(4))) float f32x4;

static __device__ __forceinline__ ushort f2bf(float f) {
    unsigned u = __float_as_uint(f);
    unsigned r = (u + 0x7fffu + ((u >> 16) & 1u)) >> 16;   // RNE
    return (ushort)r;
}
static __device__ __forceinline__ float bf_lo(unsigned x) {
    return __uint_as_float(x << 16);
}
static __device__ __forceinline__ float bf_hi(unsigned x) {
    return __uint_as_float(x & 0xffff0000u);
}

// ------------------------- gcn_norm + CSR build ----------------------------
// cells[d] accumulates ((1<<40) * count) + round(ew * 2^24); the atomic's
// return value yields this edge's rank within its dst bucket for free.
__global__ void edge_stat_kernel(const int* __restrict__ dst,
                                 const float* __restrict__ ew,
                                 unsigned long long* __restrict__ cells,
                                 int* __restrict__ rank) {
    int e = blockIdx.x * 256 + threadIdx.x;
    if (e < NE) {
        unsigned long long inc =
            (1ULL << 40) | (unsigned long long)(unsigned)rintf(ew[e] * 16777216.0f);
        unsigned long long old = atomicAdd(&cells[dst[e]], inc);
        rank[e] = (int)(old >> 40);
    }
}

__global__ void deg_finish_kernel(const unsigned long long* __restrict__ cells,
                                  int* __restrict__ cnt,
                                  float* __restrict__ dinv) {
    int i = blockIdx.x * 256 + threadIdx.x;
    if (i < NN) {
        unsigned long long c = cells[i];
        cnt[i] = (int)(c >> 40);
        float deg = 1.0f + (float)(c & ((1ULL << 40) - 1)) * (1.0f / 16777216.0f);
        dinv[i] = rsqrtf(deg);  // deg >= 1 always (self-loop)
    }
}

__global__ void scan_kernel(const int* __restrict__ cnt, int* __restrict__ rowptr, int n) {
    __shared__ int wsum[16];
    __shared__ int carry_s;
    int tid = threadIdx.x;
    int lane = tid & 63;
    int wid = tid >> 6;
    if (tid == 0) carry_s = 0;
    __syncthreads();
    for (int base = 0; base < n; base += 1024) {
        int i = base + tid;
        int v = (i < n) ? cnt[i] : 0;
        int x = v;
        #pragma unroll
        for (int o = 1; o < 64; o <<= 1) {
            int y = __shfl_up(x, o, 64);
            if (lane >= o) x += y;
        }
        if (lane == 63) wsum[wid] = x;
        __syncthreads();
        if (wid == 0) {
            int w = (lane < 16) ? wsum[lane] : 0;
            #pragma unroll
            for (int o = 1; o < 16; o <<= 1) {
                int y = __shfl_up(w, o, 64);
                if (lane >= o) w += y;
            }
            if (lane < 16) wsum[lane] = w;
        }
        __syncthreads();
        int wexcl = (wid > 0) ? wsum[wid - 1] : 0;
        int incl = x + wexcl;
        int c = carry_s;
        if (i < n) rowptr[i] = c + incl - v;
        __syncthreads();
        if (tid == 1023) carry_s = c + wsum[15];
        __syncthreads();
    }
    if (tid == 0) rowptr[n] = carry_s;
}

// Atomic-free fill: position = rowptr[dst] + rank; one 8B write per edge.
__global__ void fill_kernel(const int* __restrict__ src,
                            const int* __restrict__ dst,
                            const float* __restrict__ ew,
                            const float* __restrict__ dinv,
                            const int* __restrict__ rank,
                            const int* __restrict__ rowptr,
                            int2* __restrict__ edges2) {
    int e = blockIdx.x * 256 + threadIdx.x;
    if (e < NE) {
        int s = src[e], d = dst[e];
        float nrm = dinv[s] * ew[e] * dinv[d];
        int p = rowptr[d] + rank[e];
        edges2[p] = make_int2(s, __float_as_int(nrm));
    }
}

// ---------------------- weight transpose + bf16 cvt ------------------------
__global__ void wcvt_kernel(const float* __restrict__ Wm,
                            const float* __restrict__ Wl,
                            ushort* __restrict__ Bt) {
    int idx = blockIdx.x * 256 + threadIdx.x;
    if (idx >= 7 * 65536) return;
    int l = idx >> 16;
    int nk = idx & 65535;
    int n = nk >> 8, k = nk & 255;
    const float* W = (l < 6) ? (Wm + (size_t)l * 65536) : Wl;
    Bt[idx] = f2bf(W[k * 256 + n]);
}

// Layer-0: X[N,256] = h[N,6] @ W1[6,256], fp32 math, bf16 output.
__global__ void gemm0_kernel(const float* __restrict__ h,
                             const float* __restrict__ W1,
                             ushort* __restrict__ Xb) {
    __shared__ float hs[6];
    int i = blockIdx.x;
    int f = threadIdx.x;
    if (f < 6) hs[f] = h[i * 6 + f];
    __syncthreads();
    float s = 0.0f;
    #pragma unroll
    for (int k = 0; k < 6; ++k) s = fmaf(hs[k], W1[k * 256 + f], s);
    Xb[(size_t)i * 256 + f] = f2bf(s);
}

// ---------------- MFMA bf16 GEMM with fused BN+leakyReLU on A --------------
// C[M,256] = leaky(BN(Y))[M,256] @ Bt^T. Tile 128 rows x 256 cols (full
// width -> Y read once), BK=32, 4 waves each 128x64 (8x4 frags 16x16x32).
__launch_bounds__(256)
__global__ void gemm_bn_kernel(const float* __restrict__ Y,
                               const ushort* __restrict__ Bt,
                               const float* __restrict__ scsh,
                               ushort* __restrict__ C, int M) {
    __shared__ __align__(16) ushort As[128][40];
    __shared__ __align__(16) ushort Bs[256][40];
    __shared__ float sc_s[256], sh_s[256];
    int tid = threadIdx.x;
    sc_s[tid] = scsh[tid];
    sh_s[tid] = scsh[256 + tid];
    int lane = tid & 63, w = tid >> 6;
    int lm = lane & 15, kq = lane >> 4;
    int row0 = blockIdx.x * 128;
    int arow = tid >> 1;             // 0..127
    int ah = (tid & 1) * 16;         // k-offset 0/16
    const float4* Y4 = (const float4*)Y;

    f32x4 acc[8][4] = {};
    __syncthreads();  // sc_s/sh_s visible before first staging

    for (int k0 = 0; k0 < 256; k0 += 32) {
        // --- stage A: fp32 Y -> BN -> leaky -> bf16 ---
        {
            int grow = row0 + arow;
            float4 v[4];
            if (grow < M) {
                size_t base = (size_t)grow * 64 + ((k0 + ah) >> 2);
                #pragma unroll
                for (int q = 0; q < 4; ++q) v[q] = Y4[base + q];
            } else {
                #pragma unroll
                for (int q = 0; q < 4; ++q) v[q] = make_float4(0.f, 0.f, 0.f, 0.f);
            }
            uint packed[8];
            #pragma unroll
            for (int q = 0; q < 4; ++q) {
                int cbase = k0 + ah + q * 4;
                float4 sc = *(const float4*)&sc_s[cbase];
                float4 sh = *(const float4*)&sh_s[cbase];
                float o0 = fmaf(v[q].x, sc.x, sh.x); o0 = (o0 >= 0.f) ? o0 : 0.01f * o0;
                float o1 = fmaf(v[q].y, sc.y, sh.y); o1 = (o1 >= 0.f) ? o1 : 0.01f * o1;
                float o2 = fmaf(v[q].z, sc.z, sh.z); o2 = (o2 >= 0.f) ? o2 : 0.01f * o2;
                float o3 = fmaf(v[q].w, sc.w, sh.w); o3 = (o3 >= 0.f) ? o3 : 0.01f * o3;
                packed[q * 2 + 0] = (uint)f2bf(o0) | ((uint)f2bf(o1) << 16);
                packed[q * 2 + 1] = (uint)f2bf(o2) | ((uint)f2bf(o3) << 16);
            }
            *(uint4*)&As[arow][ah] = make_uint4(packed[0], packed[1], packed[2], packed[3]);
            *(uint4*)&As[arow][ah + 8] = make_uint4(packed[4], packed[5], packed[6], packed[7]);
        }
        // --- stage B: 256n x 32k bf16, thread tid = row n ---
        {
            const ushort* gb = Bt + (size_t)tid * 256 + k0;
            uint4 b0 = *(const uint4*)(gb + 0);
            uint4 b1 = *(const uint4*)(gb + 8);
            uint4 b2 = *(const uint4*)(gb + 16);
            uint4 b3 = *(const uint4*)(gb + 24);
            *(uint4*)&Bs[tid][0]  = b0;
            *(uint4*)&Bs[tid][8]  = b1;
            *(uint4*)&Bs[tid][16] = b2;
            *(uint4*)&Bs[tid][24] = b3;
        }
        __syncthreads();
        short8 af[8], bf[4];
        #pragma unroll
        for (int i = 0; i < 8; ++i)
            af[i] = *(const short8*)&As[i * 16 + lm][kq * 8];
        #pragma unroll
        for (int j = 0; j < 4; ++j)
            bf[j] = *(const short8*)&Bs[w * 64 + j * 16 + lm][kq * 8];
        #pragma unroll
        for (int i = 0; i < 8; ++i)
            #pragma unroll
            for (int j = 0; j < 4; ++j)
                acc[i][j] = __builtin_amdgcn_mfma_f32_16x16x32_bf16(
                    af[i], bf[j], acc[i][j], 0, 0, 0);
        __syncthreads();
    }

    // Epilogue: C/D layout col=lane&15, row=(lane>>4)*4+reg
    #pragma unroll
    for (int i = 0; i < 8; ++i) {
        #pragma unroll
        for (int j = 0; j < 4; ++j) {
            int col = w * 64 + j * 16 + lm;
            #pragma unroll
            for (int r = 0; r < 4; ++r) {
                int grow = row0 + i * 16 + kq * 4 + r;
                if (grow < M) C[(size_t)grow * 256 + col] = f2bf(acc[i][j][r]);
            }
        }
    }
}

// ---------------------- gather aggregation (bf16 X) ------------------------
// One wave per dst node; 8x unrolled edge loop for memory-level parallelism.
__global__ void agg_kernel(const ushort* __restrict__ Xb,
                           float* __restrict__ Y,
                           const int* __restrict__ rowptr,
                           const int2* __restrict__ edges2,
                           const float* __restrict__ dinv,
                           const float* __restrict__ bias) {
    int node = (blockIdx.x << 2) + (threadIdx.x >> 6);
    if (node >= NN) return;
    int lane = threadIdx.x & 63;
    const uint2* X2 = (const uint2*)Xb;
    float di = dinv[node];
    float w0 = di * di;
    uint2 v = X2[(size_t)node * 64 + lane];
    float4 bb = ((const float4*)bias)[lane];
    float ax = fmaf(w0, bf_lo(v.x), bb.x);
    float ay = fmaf(w0, bf_hi(v.x), bb.y);
    float az = fmaf(w0, bf_lo(v.y), bb.z);
    float aw = fmaf(w0, bf_hi(v.y), bb.w);
    int j = rowptr[node], jend = rowptr[node + 1];
    int jstop = j + ((jend - j) & ~7);
    for (; j < jstop; j += 8) {
        int2 e0 = edges2[j + 0], e1 = edges2[j + 1], e2 = edges2[j + 2], e3 = edges2[j + 3];
        int2 e4 = edges2[j + 4], e5 = edges2[j + 5], e6 = edges2[j + 6], e7 = edges2[j + 7];
        uint2 u0 = X2[(size_t)e0.x * 64 + lane];
        uint2 u1 = X2[(size_t)e1.x * 64 + lane];
        uint2 u2 = X2[(size_t)e2.x * 64 + lane];
        uint2 u3 = X2[(size_t)e3.x * 64 + lane];
        uint2 u4 = X2[(size_t)e4.x * 64 + lane];
        uint2 u5 = X2[(size_t)e5.x * 64 + lane];
        uint2 u6 = X2[(size_t)e6.x * 64 + lane];
        uint2 u7 = X2[(size_t)e7.x * 64 + lane];
        float t0 = __int_as_float(e0.y), t1 = __int_as_float(e1.y);
        float t2 = __int_as_float(e2.y), t3 = __int_as_float(e3.y);
        float t4 = __int_as_float(e4.y), t5 = __int_as_float(e5.y);
        float t6 = __int_as_float(e6.y), t7 = __int_as_float(e7.y);
        ax = fmaf(t0, bf_lo(u0.x), ax); ay = fmaf(t0, bf_hi(u0.x), ay);
        az = fmaf(t0, bf_lo(u0.y), az); aw = fmaf(t0, bf_hi(u0.y), aw);
        ax = fmaf(t1, bf_lo(u1.x), ax); ay = fmaf(t1, bf_hi(u1.x), ay);
        az = fmaf(t1, bf_lo(u1.y), az); aw = fmaf(t1, bf_hi(u1.y), aw);
        ax = fmaf(t2, bf_lo(u2.x), ax); ay = fmaf(t2, bf_hi(u2.x), ay);
        az = fmaf(t2, bf_lo(u2.y), az); aw = fmaf(t2, bf_hi(u2.y), aw);
        ax = fmaf(t3, bf_lo(u3.x), ax); ay = fmaf(t3, bf_hi(u3.x), ay);
        az = fmaf(t3, bf_lo(u3.y), az); aw = fmaf(t3, bf_hi(u3.y), aw);
        ax = fmaf(t4, bf_lo(u4.x), ax); ay = fmaf(t4, bf_hi(u4.x), ay);
        az = fmaf(t4, bf_lo(u4.y), az); aw = fmaf(t4, bf_hi(u4.y), aw);
        ax = fmaf(t5, bf_lo(u5.x), ax); ay = fmaf(t5, bf_hi(u5.x), ay);
        az = fmaf(t5, bf_lo(u5.y), az); aw = fmaf(t5, bf_hi(u5.y), aw);
        ax = fmaf(t6, bf_lo(u6.x), ax); ay = fmaf(t6, bf_hi(u6.x), ay);
        az = fmaf(t6, bf_lo(u6.y), az); aw = fmaf(t6, bf_hi(u6.y), aw);
        ax = fmaf(t7, bf_lo(u7.x), ax); ay = fmaf(t7, bf_hi(u7.x), ay);
        az = fmaf(t7, bf_lo(u7.y), az); aw = fmaf(t7, bf_hi(u7.y), aw);
    }
    for (; j < jend; ++j) {
        int2 e = edges2[j];
        float wt = __int_as_float(e.y);
        uint2 u = X2[(size_t)e.x * 64 + lane];
        ax = fmaf(wt, bf_lo(u.x), ax);
        ay = fmaf(wt, bf_hi(u.x), ay);
        az = fmaf(wt, bf_lo(u.y), az);
        aw = fmaf(wt, bf_hi(u.y), aw);
    }
    ((float4*)Y)[(size_t)node * 64 + lane] = make_float4(ax, ay, az, aw);
}

// ------------------------------- BatchNorm ---------------------------------
// 64 rows/block, float4 reads, LDS pre-reduce over 4 row-groups, then one
// atomic per (col, stat) per block.
__global__ void bn_stats_kernel(const float* __restrict__ Y, float* __restrict__ stats) {
    __shared__ float4 redS[4][64];
    __shared__ float4 redQ[4][64];
    int c = threadIdx.x & 63, g = threadIdx.x >> 6;
    int r0 = blockIdx.x * 64;
    int rend = min(r0 + 64, NN);
    const float4* Y4 = (const float4*)Y;
    float4 s = make_float4(0.f, 0.f, 0.f, 0.f);
    float4 q = make_float4(0.f, 0.f, 0.f, 0.f);
    for (int r = r0 + g; r < rend; r += 4) {
        float4 v = Y4[(size_t)r * 64 + c];
        s.x += v.x; s.y += v.y; s.z += v.z; s.w += v.w;
        q.x = fmaf(v.x, v.x, q.x); q.y = fmaf(v.y, v.y, q.y);
        q.z = fmaf(v.z, v.z, q.z); q.w = fmaf(v.w, v.w, q.w);
    }
    redS[g][c] = s; redQ[g][c] = q;
    __syncthreads();
    if (g == 0) {
        float4 s1 = redS[1][c], s2 = redS[2][c], s3 = redS[3][c];
        float4 q1 = redQ[1][c], q2 = redQ[2][c], q3 = redQ[3][c];
        s.x += s1.x + s2.x + s3.x; s.y += s1.y + s2.y + s3.y;
        s.z += s1.z + s2.z + s3.z; s.w += s1.w + s2.w + s3.w;
        q.x += q1.x + q2.x + q3.x; q.y += q1.y + q2.y + q3.y;
        q.z += q1.z + q2.z + q3.z; q.w += q1.w + q2.w + q3.w;
        unsafeAtomicAdd(&stats[c * 4 + 0], s.x);
        unsafeAtomicAdd(&stats[c * 4 + 1], s.y);
        unsafeAtomicAdd(&stats[c * 4 + 2], s.z);
        unsafeAtomicAdd(&stats[c * 4 + 3], s.w);
        unsafeAtomicAdd(&stats[256 + c * 4 + 0], q.x);
        unsafeAtomicAdd(&stats[256 + c * 4 + 1], q.y);
        unsafeAtomicAdd(&stats[256 + c * 4 + 2], q.z);
        unsafeAtomicAdd(&stats[256 + c * 4 + 3], q.w);
    }
}

// stats -> per-column scale/shift:  act = leaky(y*scale + shift)
__global__ void bn_finalize_kernel(const float* __restrict__ stats,
                                   const float* __restrict__ g,
                                   const float* __restrict__ be,
                                   float* __restrict__ scsh) {
    int c = threadIdx.x;
    const float invN = 1.0f / (float)NN;
    float m = stats[c] * invN;
    float var = fmaf(-m, m, stats[256 + c] * invN);
    float sc = rsqrtf(var + 1e-5f) * g[c];
    scsh[c] = sc;
    scsh[256 + c] = fmaf(-m, sc, be[c]);
}

// ---------------------------------------------------------------------------

extern "C" void kernel_launch(void* const* d_in, const int* in_sizes, int n_in,
                              void* d_out, int out_size, void* d_ws, size_t ws_size,
                              hipStream_t stream) {
    const float* h   = (const float*)d_in[0];
    const int*   ei  = (const int*)d_in[1];
    const float* ew  = (const float*)d_in[2];
    const float* W1  = (const float*)d_in[3];
    const float* b1  = (const float*)d_in[4];
    const float* g1  = (const float*)d_in[5];
    const float* be1 = (const float*)d_in[6];
    const float* Wm  = (const float*)d_in[7];
    const float* bm  = (const float*)d_in[8];
    const float* gm  = (const float*)d_in[9];
    const float* bem = (const float*)d_in[10];
    const float* Wl  = (const float*)d_in[11];
    const float* bl  = (const float*)d_in[12];

    const int* src = ei;
    const int* dst = ei + NE;

    char* ws = (char*)d_ws;
    size_t off = 0;
    auto alloc = [&](size_t bytes) { size_t o = off; off = (off + bytes + 255) & ~(size_t)255; return o; };
    ushort* Xb     = (ushort*)(ws + alloc((size_t)NN * DD * 2));
    float*  Y      = (float*) (ws + alloc((size_t)NN * DD * 4));
    ushort* Bt     = (ushort*)(ws + alloc((size_t)7 * DD * DD * 2));
    unsigned long long* cells = (unsigned long long*)(ws + alloc((size_t)NN * 8));
    float*  dinv   = (float*) (ws + alloc((size_t)NN * 4));
    float*  stats  = (float*) (ws + alloc(512 * 4));
    float*  scsh   = (float*) (ws + alloc(512 * 4));
    int*    rowptr = (int*)   (ws + alloc((size_t)(NN + 1) * 4));
    int*    cnt    = (int*)   (ws + alloc((size_t)NN * 4));
    int*    rank   = (int*)   (ws + alloc((size_t)NE * 4));
    int2*   edges2 = (int2*)  (ws + alloc((size_t)NE * 8));
    (void)ws_size;

    float* OUT = (float*)d_out;

    const int gN = (NN + 255) / 256;
    const int gE = (NE + 255) / 256;

    // --- gcn_norm + CSR build ---
    hipMemsetAsync(cells, 0, (size_t)NN * 8, stream);
    edge_stat_kernel<<<gE, 256, 0, stream>>>(dst, ew, cells, rank);
    deg_finish_kernel<<<gN, 256, 0, stream>>>(cells, cnt, dinv);
    scan_kernel<<<1, 1024, 0, stream>>>(cnt, rowptr, NN);
    fill_kernel<<<gE, 256, 0, stream>>>(src, dst, ew, dinv, rank, rowptr, edges2);

    // --- weights -> bf16 transposed ---
    wcvt_kernel<<<(7 * 65536 + 255) / 256, 256, 0, stream>>>(Wm, Wl, Bt);

    // --- layer 0 GEMM ---
    gemm0_kernel<<<NN, 256, 0, stream>>>(h, W1, Xb);

    // --- 8 layers ---
    for (int l = 0; l < 8; ++l) {
        const float* b_l = (l == 0) ? b1 : (l <= 6 ? bm + (l - 1) * 256 : bl);
        if (l >= 1) {
            const ushort* Btl = Bt + (size_t)(l - 1) * DD * DD;
            gemm_bn_kernel<<<(NN + 127) / 128, 256, 0, stream>>>(Y, Btl, scsh, Xb, NN);
        }
        float* Yl = (l == 7) ? OUT : Y;
        agg_kernel<<<(NN + 3) / 4, 256, 0, stream>>>(Xb, Yl, rowptr, edges2, dinv, b_l);
        if (l < 7) {
            const float* g_l  = (l == 0) ? g1 : gm + (l - 1) * 256;
            const float* be_l = (l == 0) ? be1 : bem + (l - 1) * 256;
            hipMemsetAsync(stats, 0, 512 * 4, stream);
            bn_stats_kernel<<<(NN + 63) / 64, 256, 0, stream>>>(Y, stats);
            bn_finalize_kernel<<<1, 256, 0, stream>>>(stats, g_l, be_l, scsh);
        }
    }
}

// Round 5
// 1081.419 us; speedup vs baseline: 1.4684x; 1.4684x over previous
//
#include <hip/hip_runtime.h>
#include <hip/hip_bf16.h>

// ---------------------------------------------------------------------------
// EncoderGAE: 8-layer GCN encoder on MI355X.
// R5: (1) bn_stats: two-stage atomic-free reduction (R4's 83us/layer was
//         latency-bound + same-line cross-XCD atomic ping-pong).
//     (2) gemm_bn back to 128x128 tile (R4's 256-wide tile tanked occupancy),
//         BN+leakyReLU still fused into A-staging.
// ---------------------------------------------------------------------------

#define NN 50000
#define NE 800000
#define DD 256

typedef __attribute__((ext_vector_type(8))) short short8;
typedef __attribute__((ext_vector_type(4))) float f32x4;

static __device__ __forceinline__ ushort f2bf(float f) {
    unsigned u = __float_as_uint(f);
    unsigned r = (u + 0x7fffu + ((u >> 16) & 1u)) >> 16;   // RNE
    return (ushort)r;
}
static __device__ __forceinline__ float bf_lo(unsigned x) {
    return __uint_as_float(x << 16);
}
static __device__ __forceinline__ float bf_hi(unsigned x) {
    return __uint_as_float(x & 0xffff0000u);
}

// ------------------------- gcn_norm + CSR build ----------------------------
// cells[d] accumulates ((1<<40) * count) + round(ew * 2^24); the atomic's
// return value yields this edge's rank within its dst bucket for free.
__global__ void edge_stat_kernel(const int* __restrict__ dst,
                                 const float* __restrict__ ew,
                                 unsigned long long* __restrict__ cells,
                                 int* __restrict__ rank) {
    int e = blockIdx.x * 256 + threadIdx.x;
    if (e < NE) {
        unsigned long long inc =
            (1ULL << 40) | (unsigned long long)(unsigned)rintf(ew[e] * 16777216.0f);
        unsigned long long old = atomicAdd(&cells[dst[e]], inc);
        rank[e] = (int)(old >> 40);
    }
}

__global__ void deg_finish_kernel(const unsigned long long* __restrict__ cells,
                                  int* __restrict__ cnt,
                                  float* __restrict__ dinv) {
    int i = blockIdx.x * 256 + threadIdx.x;
    if (i < NN) {
        unsigned long long c = cells[i];
        cnt[i] = (int)(c >> 40);
        float deg = 1.0f + (float)(c & ((1ULL << 40) - 1)) * (1.0f / 16777216.0f);
        dinv[i] = rsqrtf(deg);  // deg >= 1 always (self-loop)
    }
}

__global__ void scan_kernel(const int* __restrict__ cnt, int* __restrict__ rowptr, int n) {
    __shared__ int wsum[16];
    __shared__ int carry_s;
    int tid = threadIdx.x;
    int lane = tid & 63;
    int wid = tid >> 6;
    if (tid == 0) carry_s = 0;
    __syncthreads();
    for (int base = 0; base < n; base += 1024) {
        int i = base + tid;
        int v = (i < n) ? cnt[i] : 0;
        int x = v;
        #pragma unroll
        for (int o = 1; o < 64; o <<= 1) {
            int y = __shfl_up(x, o, 64);
            if (lane >= o) x += y;
        }
        if (lane == 63) wsum[wid] = x;
        __syncthreads();
        if (wid == 0) {
            int w = (lane < 16) ? wsum[lane] : 0;
            #pragma unroll
            for (int o = 1; o < 16; o <<= 1) {
                int y = __shfl_up(w, o, 64);
                if (lane >= o) w += y;
            }
            if (lane < 16) wsum[lane] = w;
        }
        __syncthreads();
        int wexcl = (wid > 0) ? wsum[wid - 1] : 0;
        int incl = x + wexcl;
        int c = carry_s;
        if (i < n) rowptr[i] = c + incl - v;
        __syncthreads();
        if (tid == 1023) carry_s = c + wsum[15];
        __syncthreads();
    }
    if (tid == 0) rowptr[n] = carry_s;
}

// Atomic-free fill: position = rowptr[dst] + rank; one 8B write per edge.
__global__ void fill_kernel(const int* __restrict__ src,
                            const int* __restrict__ dst,
                            const float* __restrict__ ew,
                            const float* __restrict__ dinv,
                            const int* __restrict__ rank,
                            const int* __restrict__ rowptr,
                            int2* __restrict__ edges2) {
    int e = blockIdx.x * 256 + threadIdx.x;
    if (e < NE) {
        int s = src[e], d = dst[e];
        float nrm = dinv[s] * ew[e] * dinv[d];
        int p = rowptr[d] + rank[e];
        edges2[p] = make_int2(s, __float_as_int(nrm));
    }
}

// ---------------------- weight transpose + bf16 cvt ------------------------
__global__ void wcvt_kernel(const float* __restrict__ Wm,
                            const float* __restrict__ Wl,
                            ushort* __restrict__ Bt) {
    int idx = blockIdx.x * 256 + threadIdx.x;
    if (idx >= 7 * 65536) return;
    int l = idx >> 16;
    int nk = idx & 65535;
    int n = nk >> 8, k = nk & 255;
    const float* W = (l < 6) ? (Wm + (size_t)l * 65536) : Wl;
    Bt[idx] = f2bf(W[k * 256 + n]);
}

// Layer-0: X[N,256] = h[N,6] @ W1[6,256], fp32 math, bf16 output.
__global__ void gemm0_kernel(const float* __restrict__ h,
                             const float* __restrict__ W1,
                             ushort* __restrict__ Xb) {
    __shared__ float hs[6];
    int i = blockIdx.x;
    int f = threadIdx.x;
    if (f < 6) hs[f] = h[i * 6 + f];
    __syncthreads();
    float s = 0.0f;
    #pragma unroll
    for (int k = 0; k < 6; ++k) s = fmaf(hs[k], W1[k * 256 + f], s);
    Xb[(size_t)i * 256 + f] = f2bf(s);
}

// ---------------- MFMA bf16 GEMM with fused BN+leakyReLU on A --------------
// C[M,256] = leaky(BN(Y)) @ Bt^T. 128x128 tile (R3 shape), BK=32, 4 waves
// each 64x64 (4x4 frags of 16x16x32). A staged from fp32 Y with BN applied.
__launch_bounds__(256)
__global__ void gemm_bn_kernel(const float* __restrict__ Y,
                               const ushort* __restrict__ Bt,
                               const float* __restrict__ scsh,
                               ushort* __restrict__ C, int M) {
    __shared__ __align__(16) ushort As[128][40];
    __shared__ __align__(16) ushort Bs[128][40];
    __shared__ float sc_s[256], sh_s[256];
    int tid = threadIdx.x;
    sc_s[tid] = scsh[tid];
    sh_s[tid] = scsh[256 + tid];
    int lane = tid & 63, w = tid >> 6;
    int wr = w >> 1, wc = w & 1;
    int lm = lane & 15, kq = lane >> 4;
    int row0 = blockIdx.y * 128;
    int col0 = blockIdx.x * 128;
    int arow = tid >> 1;             // 0..127 (A staging row)
    int ah = (tid & 1) * 16;         // A k-offset 0/16
    int sr = tid & 127;              // B staging row
    int ss = tid >> 7;               // B k-half
    const float4* Y4 = (const float4*)Y;

    f32x4 acc[4][4] = {};
    __syncthreads();  // sc_s/sh_s visible

    for (int k0 = 0; k0 < 256; k0 += 32) {
        // --- stage A: fp32 Y -> BN -> leaky -> bf16, 16 elems/thread ---
        {
            int grow = row0 + arow;
            float4 v[4];
            if (grow < M) {
                size_t base = (size_t)grow * 64 + ((k0 + ah) >> 2);
                #pragma unroll
                for (int q = 0; q < 4; ++q) v[q] = Y4[base + q];
            } else {
                #pragma unroll
                for (int q = 0; q < 4; ++q) v[q] = make_float4(0.f, 0.f, 0.f, 0.f);
            }
            uint packed[8];
            #pragma unroll
            for (int q = 0; q < 4; ++q) {
                int cbase = k0 + ah + q * 4;
                float4 sc = *(const float4*)&sc_s[cbase];
                float4 sh = *(const float4*)&sh_s[cbase];
                float o0 = fmaf(v[q].x, sc.x, sh.x); o0 = (o0 >= 0.f) ? o0 : 0.01f * o0;
                float o1 = fmaf(v[q].y, sc.y, sh.y); o1 = (o1 >= 0.f) ? o1 : 0.01f * o1;
                float o2 = fmaf(v[q].z, sc.z, sh.z); o2 = (o2 >= 0.f) ? o2 : 0.01f * o2;
                float o3 = fmaf(v[q].w, sc.w, sh.w); o3 = (o3 >= 0.f) ? o3 : 0.01f * o3;
                packed[q * 2 + 0] = (uint)f2bf(o0) | ((uint)f2bf(o1) << 16);
                packed[q * 2 + 1] = (uint)f2bf(o2) | ((uint)f2bf(o3) << 16);
            }
            *(uint4*)&As[arow][ah] = make_uint4(packed[0], packed[1], packed[2], packed[3]);
            *(uint4*)&As[arow][ah + 8] = make_uint4(packed[4], packed[5], packed[6], packed[7]);
        }
        // --- stage B: bf16, 16 elems/thread ---
        {
            const ushort* gb = Bt + (size_t)(col0 + sr) * 256 + k0 + ss * 16;
            uint4 bp = *(const uint4*)gb;
            uint4 bq = *(const uint4*)(gb + 8);
            *(uint4*)&Bs[sr][ss * 16] = bp;
            *(uint4*)&Bs[sr][ss * 16 + 8] = bq;
        }
        __syncthreads();
        short8 af[4], bf[4];
        #pragma unroll
        for (int i = 0; i < 4; ++i)
            af[i] = *(const short8*)&As[wr * 64 + i * 16 + lm][kq * 8];
        #pragma unroll
        for (int j = 0; j < 4; ++j)
            bf[j] = *(const short8*)&Bs[wc * 64 + j * 16 + lm][kq * 8];
        #pragma unroll
        for (int i = 0; i < 4; ++i)
            #pragma unroll
            for (int j = 0; j < 4; ++j)
                acc[i][j] = __builtin_amdgcn_mfma_f32_16x16x32_bf16(
                    af[i], bf[j], acc[i][j], 0, 0, 0);
        __syncthreads();
    }

    // Epilogue: C/D layout col=lane&15, row=(lane>>4)*4+reg
    #pragma unroll
    for (int i = 0; i < 4; ++i) {
        #pragma unroll
        for (int j = 0; j < 4; ++j) {
            int col = col0 + wc * 64 + j * 16 + lm;
            #pragma unroll
            for (int r = 0; r < 4; ++r) {
                int grow = row0 + wr * 64 + i * 16 + kq * 4 + r;
                if (grow < M) C[(size_t)grow * 256 + col] = f2bf(acc[i][j][r]);
            }
        }
    }
}

// ---------------------- gather aggregation (bf16 X) ------------------------
__global__ void agg_kernel(const ushort* __restrict__ Xb,
                           float* __restrict__ Y,
                           const int* __restrict__ rowptr,
                           const int2* __restrict__ edges2,
                           const float* __restrict__ dinv,
                           const float* __restrict__ bias) {
    int node = (blockIdx.x << 2) + (threadIdx.x >> 6);
    if (node >= NN) return;
    int lane = threadIdx.x & 63;
    const uint2* X2 = (const uint2*)Xb;
    float di = dinv[node];
    float w0 = di * di;
    uint2 v = X2[(size_t)node * 64 + lane];
    float4 bb = ((const float4*)bias)[lane];
    float ax = fmaf(w0, bf_lo(v.x), bb.x);
    float ay = fmaf(w0, bf_hi(v.x), bb.y);
    float az = fmaf(w0, bf_lo(v.y), bb.z);
    float aw = fmaf(w0, bf_hi(v.y), bb.w);
    int j = rowptr[node], jend = rowptr[node + 1];
    int jstop = j + ((jend - j) & ~7);
    for (; j < jstop; j += 8) {
        int2 e0 = edges2[j + 0], e1 = edges2[j + 1], e2 = edges2[j + 2], e3 = edges2[j + 3];
        int2 e4 = edges2[j + 4], e5 = edges2[j + 5], e6 = edges2[j + 6], e7 = edges2[j + 7];
        uint2 u0 = X2[(size_t)e0.x * 64 + lane];
        uint2 u1 = X2[(size_t)e1.x * 64 + lane];
        uint2 u2 = X2[(size_t)e2.x * 64 + lane];
        uint2 u3 = X2[(size_t)e3.x * 64 + lane];
        uint2 u4 = X2[(size_t)e4.x * 64 + lane];
        uint2 u5 = X2[(size_t)e5.x * 64 + lane];
        uint2 u6 = X2[(size_t)e6.x * 64 + lane];
        uint2 u7 = X2[(size_t)e7.x * 64 + lane];
        float t0 = __int_as_float(e0.y), t1 = __int_as_float(e1.y);
        float t2 = __int_as_float(e2.y), t3 = __int_as_float(e3.y);
        float t4 = __int_as_float(e4.y), t5 = __int_as_float(e5.y);
        float t6 = __int_as_float(e6.y), t7 = __int_as_float(e7.y);
        ax = fmaf(t0, bf_lo(u0.x), ax); ay = fmaf(t0, bf_hi(u0.x), ay);
        az = fmaf(t0, bf_lo(u0.y), az); aw = fmaf(t0, bf_hi(u0.y), aw);
        ax = fmaf(t1, bf_lo(u1.x), ax); ay = fmaf(t1, bf_hi(u1.x), ay);
        az = fmaf(t1, bf_lo(u1.y), az); aw = fmaf(t1, bf_hi(u1.y), aw);
        ax = fmaf(t2, bf_lo(u2.x), ax); ay = fmaf(t2, bf_hi(u2.x), ay);
        az = fmaf(t2, bf_lo(u2.y), az); aw = fmaf(t2, bf_hi(u2.y), aw);
        ax = fmaf(t3, bf_lo(u3.x), ax); ay = fmaf(t3, bf_hi(u3.x), ay);
        az = fmaf(t3, bf_lo(u3.y), az); aw = fmaf(t3, bf_hi(u3.y), aw);
        ax = fmaf(t4, bf_lo(u4.x), ax); ay = fmaf(t4, bf_hi(u4.x), ay);
        az = fmaf(t4, bf_lo(u4.y), az); aw = fmaf(t4, bf_hi(u4.y), aw);
        ax = fmaf(t5, bf_lo(u5.x), ax); ay = fmaf(t5, bf_hi(u5.x), ay);
        az = fmaf(t5, bf_lo(u5.y), az); aw = fmaf(t5, bf_hi(u5.y), aw);
        ax = fmaf(t6, bf_lo(u6.x), ax); ay = fmaf(t6, bf_hi(u6.x), ay);
        az = fmaf(t6, bf_lo(u6.y), az); aw = fmaf(t6, bf_hi(u6.y), aw);
        ax = fmaf(t7, bf_lo(u7.x), ax); ay = fmaf(t7, bf_hi(u7.x), ay);
        az = fmaf(t7, bf_lo(u7.y), az); aw = fmaf(t7, bf_hi(u7.y), aw);
    }
    for (; j < jend; ++j) {
        int2 e = edges2[j];
        float wt = __int_as_float(e.y);
        uint2 u = X2[(size_t)e.x * 64 + lane];
        ax = fmaf(wt, bf_lo(u.x), ax);
        ay = fmaf(wt, bf_hi(u.x), ay);
        az = fmaf(wt, bf_lo(u.y), az);
        aw = fmaf(wt, bf_hi(u.y), aw);
    }
    ((float4*)Y)[(size_t)node * 64 + lane] = make_float4(ax, ay, az, aw);
}

// ------------------------------- BatchNorm ---------------------------------
// Stage A: 256 blocks x 196 rows, 8 independent float4 loads in flight,
// LDS reduce over 4 row-groups, write private partial row (NO atomics).
#define BN_RPB 196
__global__ void bn_stats_kernel(const float* __restrict__ Y, float* __restrict__ partials) {
    __shared__ float4 redS[4][64];
    __shared__ float4 redQ[4][64];
    int c = threadIdx.x & 63, g = threadIdx.x >> 6;
    int r0 = blockIdx.x * BN_RPB;
    int rend = min(r0 + BN_RPB, NN);
    const float4* Y4 = (const float4*)Y;
    float4 s = make_float4(0.f, 0.f, 0.f, 0.f);
    float4 q = make_float4(0.f, 0.f, 0.f, 0.f);
    int r = r0 + g;
    for (; r + 28 < rend; r += 32) {
        float4 v0 = Y4[(size_t)(r +  0) * 64 + c];
        float4 v1 = Y4[(size_t)(r +  4) * 64 + c];
        float4 v2 = Y4[(size_t)(r +  8) * 64 + c];
        float4 v3 = Y4[(size_t)(r + 12) * 64 + c];
        float4 v4 = Y4[(size_t)(r + 16) * 64 + c];
        float4 v5 = Y4[(size_t)(r + 20) * 64 + c];
        float4 v6 = Y4[(size_t)(r + 24) * 64 + c];
        float4 v7 = Y4[(size_t)(r + 28) * 64 + c];
        s.x += v0.x; s.y += v0.y; s.z += v0.z; s.w += v0.w;
        q.x = fmaf(v0.x, v0.x, q.x); q.y = fmaf(v0.y, v0.y, q.y);
        q.z = fmaf(v0.z, v0.z, q.z); q.w = fmaf(v0.w, v0.w, q.w);
        s.x += v1.x; s.y += v1.y; s.z += v1.z; s.w += v1.w;
        q.x = fmaf(v1.x, v1.x, q.x); q.y = fmaf(v1.y, v1.y, q.y);
        q.z = fmaf(v1.z, v1.z, q.z); q.w = fmaf(v1.w, v1.w, q.w);
        s.x += v2.x; s.y += v2.y; s.z += v2.z; s.w += v2.w;
        q.x = fmaf(v2.x, v2.x, q.x); q.y = fmaf(v2.y, v2.y, q.y);
        q.z = fmaf(v2.z, v2.z, q.z); q.w = fmaf(v2.w, v2.w, q.w);
        s.x += v3.x; s.y += v3.y; s.z += v3.z; s.w += v3.w;
        q.x = fmaf(v3.x, v3.x, q.x); q.y = fmaf(v3.y, v3.y, q.y);
        q.z = fmaf(v3.z, v3.z, q.z); q.w = fmaf(v3.w, v3.w, q.w);
        s.x += v4.x; s.y += v4.y; s.z += v4.z; s.w += v4.w;
        q.x = fmaf(v4.x, v4.x, q.x); q.y = fmaf(v4.y, v4.y, q.y);
        q.z = fmaf(v4.z, v4.z, q.z); q.w = fmaf(v4.w, v4.w, q.w);
        s.x += v5.x; s.y += v5.y; s.z += v5.z; s.w += v5.w;
        q.x = fmaf(v5.x, v5.x, q.x); q.y = fmaf(v5.y, v5.y, q.y);
        q.z = fmaf(v5.z, v5.z, q.z); q.w = fmaf(v5.w, v5.w, q.w);
        s.x += v6.x; s.y += v6.y; s.z += v6.z; s.w += v6.w;
        q.x = fmaf(v6.x, v6.x, q.x); q.y = fmaf(v6.y, v6.y, q.y);
        q.z = fmaf(v6.z, v6.z, q.z); q.w = fmaf(v6.w, v6.w, q.w);
        s.x += v7.x; s.y += v7.y; s.z += v7.z; s.w += v7.w;
        q.x = fmaf(v7.x, v7.x, q.x); q.y = fmaf(v7.y, v7.y, q.y);
        q.z = fmaf(v7.z, v7.z, q.z); q.w = fmaf(v7.w, v7.w, q.w);
    }
    for (; r < rend; r += 4) {
        float4 v = Y4[(size_t)r * 64 + c];
        s.x += v.x; s.y += v.y; s.z += v.z; s.w += v.w;
        q.x = fmaf(v.x, v.x, q.x); q.y = fmaf(v.y, v.y, q.y);
        q.z = fmaf(v.z, v.z, q.z); q.w = fmaf(v.w, v.w, q.w);
    }
    redS[g][c] = s; redQ[g][c] = q;
    __syncthreads();
    if (g == 0) {
        float4 s1 = redS[1][c], s2 = redS[2][c], s3 = redS[3][c];
        float4 q1 = redQ[1][c], q2 = redQ[2][c], q3 = redQ[3][c];
        s.x += s1.x + s2.x + s3.x; s.y += s1.y + s2.y + s3.y;
        s.z += s1.z + s2.z + s3.z; s.w += s1.w + s2.w + s3.w;
        q.x += q1.x + q2.x + q3.x; q.y += q1.y + q2.y + q3.y;
        q.z += q1.z + q2.z + q3.z; q.w += q1.w + q2.w + q3.w;
        float* P = partials + (size_t)blockIdx.x * 512;
        *(float4*)&P[c * 4] = s;
        *(float4*)&P[256 + c * 4] = q;
    }
}

// Stage B + finalize: 8 blocks x 32 cols; reduce 256 partial rows, emit
// scale/shift:  act = leaky(y*scale + shift).
__global__ void bn_finalize_kernel(const float* __restrict__ partials,
                                   const float* __restrict__ g,
                                   const float* __restrict__ be,
                                   float* __restrict__ scsh) {
    __shared__ float rs[8][32], rq[8][32];
    int cl = threadIdx.x & 31, gr = threadIdx.x >> 5;
    int col = blockIdx.x * 32 + cl;
    float s = 0.f, q = 0.f;
    #pragma unroll 4
    for (int r = gr; r < 256; r += 8) {
        s += partials[(size_t)r * 512 + col];
        q += partials[(size_t)r * 512 + 256 + col];
    }
    rs[gr][cl] = s; rq[gr][cl] = q;
    __syncthreads();
    if (gr == 0) {
        #pragma unroll
        for (int i = 1; i < 8; ++i) { s += rs[i][cl]; q += rq[i][cl]; }
        const float invN = 1.0f / (float)NN;
        float m = s * invN;
        float var = fmaf(-m, m, q * invN);
        float sc = rsqrtf(var + 1e-5f) * g[col];
        scsh[col] = sc;
        scsh[256 + col] = fmaf(-m, sc, be[col]);
    }
}

// ---------------------------------------------------------------------------

extern "C" void kernel_launch(void* const* d_in, const int* in_sizes, int n_in,
                              void* d_out, int out_size, void* d_ws, size_t ws_size,
                              hipStream_t stream) {
    const float* h   = (const float*)d_in[0];
    const int*   ei  = (const int*)d_in[1];
    const float* ew  = (const float*)d_in[2];
    const float* W1  = (const float*)d_in[3];
    const float* b1  = (const float*)d_in[4];
    const float* g1  = (const float*)d_in[5];
    const float* be1 = (const float*)d_in[6];
    const float* Wm  = (const float*)d_in[7];
    const float* bm  = (const float*)d_in[8];
    const float* gm  = (const float*)d_in[9];
    const float* bem = (const float*)d_in[10];
    const float* Wl  = (const float*)d_in[11];
    const float* bl  = (const float*)d_in[12];

    const int* src = ei;
    const int* dst = ei + NE;

    char* ws = (char*)d_ws;
    size_t off = 0;
    auto alloc = [&](size_t bytes) { size_t o = off; off = (off + bytes + 255) & ~(size_t)255; return o; };
    ushort* Xb      = (ushort*)(ws + alloc((size_t)NN * DD * 2));
    float*  Y       = (float*) (ws + alloc((size_t)NN * DD * 4));
    ushort* Bt      = (ushort*)(ws + alloc((size_t)7 * DD * DD * 2));
    unsigned long long* cells = (unsigned long long*)(ws + alloc((size_t)NN * 8));
    float*  dinv    = (float*) (ws + alloc((size_t)NN * 4));
    float*  partials= (float*) (ws + alloc((size_t)256 * 512 * 4));
    float*  scsh    = (float*) (ws + alloc(512 * 4));
    int*    rowptr  = (int*)   (ws + alloc((size_t)(NN + 1) * 4));
    int*    cnt     = (int*)   (ws + alloc((size_t)NN * 4));
    int*    rank    = (int*)   (ws + alloc((size_t)NE * 4));
    int2*   edges2  = (int2*)  (ws + alloc((size_t)NE * 8));
    (void)ws_size;

    float* OUT = (float*)d_out;

    const int gN = (NN + 255) / 256;
    const int gE = (NE + 255) / 256;

    // --- gcn_norm + CSR build ---
    hipMemsetAsync(cells, 0, (size_t)NN * 8, stream);
    edge_stat_kernel<<<gE, 256, 0, stream>>>(dst, ew, cells, rank);
    deg_finish_kernel<<<gN, 256, 0, stream>>>(cells, cnt, dinv);
    scan_kernel<<<1, 1024, 0, stream>>>(cnt, rowptr, NN);
    fill_kernel<<<gE, 256, 0, stream>>>(src, dst, ew, dinv, rank, rowptr, edges2);

    // --- weights -> bf16 transposed ---
    wcvt_kernel<<<(7 * 65536 + 255) / 256, 256, 0, stream>>>(Wm, Wl, Bt);

    // --- layer 0 GEMM ---
    gemm0_kernel<<<NN, 256, 0, stream>>>(h, W1, Xb);

    // --- 8 layers ---
    for (int l = 0; l < 8; ++l) {
        const float* b_l = (l == 0) ? b1 : (l <= 6 ? bm + (l - 1) * 256 : bl);
        if (l >= 1) {
            const ushort* Btl = Bt + (size_t)(l - 1) * DD * DD;
            dim3 grid(2, (NN + 127) / 128);
            gemm_bn_kernel<<<grid, 256, 0, stream>>>(Y, Btl, scsh, Xb, NN);
        }
        float* Yl = (l == 7) ? OUT : Y;
        agg_kernel<<<(NN + 3) / 4, 256, 0, stream>>>(Xb, Yl, rowptr, edges2, dinv, b_l);
        if (l < 7) {
            const float* g_l  = (l == 0) ? g1 : gm + (l - 1) * 256;
            const float* be_l = (l == 0) ? be1 : bem + (l - 1) * 256;
            bn_stats_kernel<<<256, 256, 0, stream>>>(Y, partials);
            bn_finalize_kernel<<<8, 256, 0, stream>>>(partials, g_l, be_l, scsh);
        }
    }
}

// Round 6
// 988.623 us; speedup vs baseline: 1.6062x; 1.0939x over previous
//
#include <hip/hip_runtime.h>
#include <hip/hip_bf16.h>

// ---------------------------------------------------------------------------
// EncoderGAE: 8-layer GCN encoder on MI355X.
// R6: Y (aggregation output / BN input / GEMM-A input) stored as bf16 for
//     layers 0..6 — halves agg write, bn_stats read, and gemm A-staging read.
//     Layer 7 agg writes fp32 directly to d_out.
// ---------------------------------------------------------------------------

#define NN 50000
#define NE 800000
#define DD 256

typedef __attribute__((ext_vector_type(8))) short short8;
typedef __attribute__((ext_vector_type(4))) float f32x4;

static __device__ __forceinline__ ushort f2bf(float f) {
    unsigned u = __float_as_uint(f);
    unsigned r = (u + 0x7fffu + ((u >> 16) & 1u)) >> 16;   // RNE
    return (ushort)r;
}
static __device__ __forceinline__ float bf_lo(unsigned x) {
    return __uint_as_float(x << 16);
}
static __device__ __forceinline__ float bf_hi(unsigned x) {
    return __uint_as_float(x & 0xffff0000u);
}

// ------------------------- gcn_norm + CSR build ----------------------------
__global__ void edge_stat_kernel(const int* __restrict__ dst,
                                 const float* __restrict__ ew,
                                 unsigned long long* __restrict__ cells,
                                 int* __restrict__ rank) {
    int e = blockIdx.x * 256 + threadIdx.x;
    if (e < NE) {
        unsigned long long inc =
            (1ULL << 40) | (unsigned long long)(unsigned)rintf(ew[e] * 16777216.0f);
        unsigned long long old = atomicAdd(&cells[dst[e]], inc);
        rank[e] = (int)(old >> 40);
    }
}

__global__ void deg_finish_kernel(const unsigned long long* __restrict__ cells,
                                  int* __restrict__ cnt,
                                  float* __restrict__ dinv) {
    int i = blockIdx.x * 256 + threadIdx.x;
    if (i < NN) {
        unsigned long long c = cells[i];
        cnt[i] = (int)(c >> 40);
        float deg = 1.0f + (float)(c & ((1ULL << 40) - 1)) * (1.0f / 16777216.0f);
        dinv[i] = rsqrtf(deg);  // deg >= 1 always (self-loop)
    }
}

__global__ void scan_kernel(const int* __restrict__ cnt, int* __restrict__ rowptr, int n) {
    __shared__ int wsum[16];
    __shared__ int carry_s;
    int tid = threadIdx.x;
    int lane = tid & 63;
    int wid = tid >> 6;
    if (tid == 0) carry_s = 0;
    __syncthreads();
    for (int base = 0; base < n; base += 1024) {
        int i = base + tid;
        int v = (i < n) ? cnt[i] : 0;
        int x = v;
        #pragma unroll
        for (int o = 1; o < 64; o <<= 1) {
            int y = __shfl_up(x, o, 64);
            if (lane >= o) x += y;
        }
        if (lane == 63) wsum[wid] = x;
        __syncthreads();
        if (wid == 0) {
            int w = (lane < 16) ? wsum[lane] : 0;
            #pragma unroll
            for (int o = 1; o < 16; o <<= 1) {
                int y = __shfl_up(w, o, 64);
                if (lane >= o) w += y;
            }
            if (lane < 16) wsum[lane] = w;
        }
        __syncthreads();
        int wexcl = (wid > 0) ? wsum[wid - 1] : 0;
        int incl = x + wexcl;
        int c = carry_s;
        if (i < n) rowptr[i] = c + incl - v;
        __syncthreads();
        if (tid == 1023) carry_s = c + wsum[15];
        __syncthreads();
    }
    if (tid == 0) rowptr[n] = carry_s;
}

// Atomic-free fill: position = rowptr[dst] + rank; one 8B write per edge.
__global__ void fill_kernel(const int* __restrict__ src,
                            const int* __restrict__ dst,
                            const float* __restrict__ ew,
                            const float* __restrict__ dinv,
                            const int* __restrict__ rank,
                            const int* __restrict__ rowptr,
                            int2* __restrict__ edges2) {
    int e = blockIdx.x * 256 + threadIdx.x;
    if (e < NE) {
        int s = src[e], d = dst[e];
        float nrm = dinv[s] * ew[e] * dinv[d];
        int p = rowptr[d] + rank[e];
        edges2[p] = make_int2(s, __float_as_int(nrm));
    }
}

// ---------------------- weight transpose + bf16 cvt ------------------------
__global__ void wcvt_kernel(const float* __restrict__ Wm,
                            const float* __restrict__ Wl,
                            ushort* __restrict__ Bt) {
    int idx = blockIdx.x * 256 + threadIdx.x;
    if (idx >= 7 * 65536) return;
    int l = idx >> 16;
    int nk = idx & 65535;
    int n = nk >> 8, k = nk & 255;
    const float* W = (l < 6) ? (Wm + (size_t)l * 65536) : Wl;
    Bt[idx] = f2bf(W[k * 256 + n]);
}

// Layer-0: X[N,256] = h[N,6] @ W1[6,256], fp32 math, bf16 output.
__global__ void gemm0_kernel(const float* __restrict__ h,
                             const float* __restrict__ W1,
                             ushort* __restrict__ Xb) {
    __shared__ float hs[6];
    int i = blockIdx.x;
    int f = threadIdx.x;
    if (f < 6) hs[f] = h[i * 6 + f];
    __syncthreads();
    float s = 0.0f;
    #pragma unroll
    for (int k = 0; k < 6; ++k) s = fmaf(hs[k], W1[k * 256 + f], s);
    Xb[(size_t)i * 256 + f] = f2bf(s);
}

// ---------------- MFMA bf16 GEMM with fused BN+leakyReLU on A --------------
// C[M,256] = leaky(BN(Yb)) @ Bt^T. 128x128 tile, BK=32, 4 waves each 64x64.
// A staged from bf16 Yb with BN scale/shift + leaky applied in registers.
__launch_bounds__(256)
__global__ void gemm_bn_kernel(const ushort* __restrict__ Yb,
                               const ushort* __restrict__ Bt,
                               const float* __restrict__ scsh,
                               ushort* __restrict__ C, int M) {
    __shared__ __align__(16) ushort As[128][40];
    __shared__ __align__(16) ushort Bs[128][40];
    __shared__ float sc_s[256], sh_s[256];
    int tid = threadIdx.x;
    sc_s[tid] = scsh[tid];
    sh_s[tid] = scsh[256 + tid];
    int lane = tid & 63, w = tid >> 6;
    int wr = w >> 1, wc = w & 1;
    int lm = lane & 15, kq = lane >> 4;
    int row0 = blockIdx.y * 128;
    int col0 = blockIdx.x * 128;
    int arow = tid >> 1;             // 0..127 (A staging row)
    int ah = (tid & 1) * 16;         // A k-offset 0/16
    int sr = tid & 127;              // B staging row
    int ss = tid >> 7;               // B k-half

    f32x4 acc[4][4] = {};
    __syncthreads();  // sc_s/sh_s visible

    for (int k0 = 0; k0 < 256; k0 += 32) {
        // --- stage A: bf16 Yb -> BN -> leaky -> bf16, 16 elems/thread ---
        {
            int grow = row0 + arow;
            uint4 p = make_uint4(0, 0, 0, 0), q = make_uint4(0, 0, 0, 0);
            if (grow < M) {
                const ushort* gp = Yb + (size_t)grow * 256 + k0 + ah;
                p = *(const uint4*)gp;
                q = *(const uint4*)(gp + 8);
            }
            uint in[8] = {p.x, p.y, p.z, p.w, q.x, q.y, q.z, q.w};
            uint packed[8];
            #pragma unroll
            for (int t = 0; t < 8; ++t) {
                int cb = k0 + ah + t * 2;
                float y0 = bf_lo(in[t]);
                float y1 = bf_hi(in[t]);
                float o0 = fmaf(y0, sc_s[cb + 0], sh_s[cb + 0]);
                float o1 = fmaf(y1, sc_s[cb + 1], sh_s[cb + 1]);
                o0 = (o0 >= 0.f) ? o0 : 0.01f * o0;
                o1 = (o1 >= 0.f) ? o1 : 0.01f * o1;
                packed[t] = (uint)f2bf(o0) | ((uint)f2bf(o1) << 16);
            }
            *(uint4*)&As[arow][ah] = make_uint4(packed[0], packed[1], packed[2], packed[3]);
            *(uint4*)&As[arow][ah + 8] = make_uint4(packed[4], packed[5], packed[6], packed[7]);
        }
        // --- stage B: bf16, 16 elems/thread ---
        {
            const ushort* gb = Bt + (size_t)(col0 + sr) * 256 + k0 + ss * 16;
            uint4 bp = *(const uint4*)gb;
            uint4 bq = *(const uint4*)(gb + 8);
            *(uint4*)&Bs[sr][ss * 16] = bp;
            *(uint4*)&Bs[sr][ss * 16 + 8] = bq;
        }
        __syncthreads();
        short8 af[4], bf[4];
        #pragma unroll
        for (int i = 0; i < 4; ++i)
            af[i] = *(const short8*)&As[wr * 64 + i * 16 + lm][kq * 8];
        #pragma unroll
        for (int j = 0; j < 4; ++j)
            bf[j] = *(const short8*)&Bs[wc * 64 + j * 16 + lm][kq * 8];
        #pragma unroll
        for (int i = 0; i < 4; ++i)
            #pragma unroll
            for (int j = 0; j < 4; ++j)
                acc[i][j] = __builtin_amdgcn_mfma_f32_16x16x32_bf16(
                    af[i], bf[j], acc[i][j], 0, 0, 0);
        __syncthreads();
    }

    // Epilogue: C/D layout col=lane&15, row=(lane>>4)*4+reg
    #pragma unroll
    for (int i = 0; i < 4; ++i) {
        #pragma unroll
        for (int j = 0; j < 4; ++j) {
            int col = col0 + wc * 64 + j * 16 + lm;
            #pragma unroll
            for (int r = 0; r < 4; ++r) {
                int grow = row0 + wr * 64 + i * 16 + kq * 4 + r;
                if (grow < M) C[(size_t)grow * 256 + col] = f2bf(acc[i][j][r]);
            }
        }
    }
}

// ---------------------- gather aggregation (bf16 X) ------------------------
// One wave per dst node; 8x unrolled edge loop. Output: bf16 Yb (layers 0-6)
// or fp32 OUT (layer 7), selected by wave-uniform flag.
__global__ void agg_kernel(const ushort* __restrict__ Xb,
                           ushort* __restrict__ Yb,
                           float* __restrict__ Yf,
                           const int* __restrict__ rowptr,
                           const int2* __restrict__ edges2,
                           const float* __restrict__ dinv,
                           const float* __restrict__ bias,
                           int out_bf16) {
    int node = (blockIdx.x << 2) + (threadIdx.x >> 6);
    if (node >= NN) return;
    int lane = threadIdx.x & 63;
    const uint2* X2 = (const uint2*)Xb;
    float di = dinv[node];
    float w0 = di * di;
    uint2 v = X2[(size_t)node * 64 + lane];
    float4 bb = ((const float4*)bias)[lane];
    float ax = fmaf(w0, bf_lo(v.x), bb.x);
    float ay = fmaf(w0, bf_hi(v.x), bb.y);
    float az = fmaf(w0, bf_lo(v.y), bb.z);
    float aw = fmaf(w0, bf_hi(v.y), bb.w);
    int j = rowptr[node], jend = rowptr[node + 1];
    int jstop = j + ((jend - j) & ~7);
    for (; j < jstop; j += 8) {
        int2 e0 = edges2[j + 0], e1 = edges2[j + 1], e2 = edges2[j + 2], e3 = edges2[j + 3];
        int2 e4 = edges2[j + 4], e5 = edges2[j + 5], e6 = edges2[j + 6], e7 = edges2[j + 7];
        uint2 u0 = X2[(size_t)e0.x * 64 + lane];
        uint2 u1 = X2[(size_t)e1.x * 64 + lane];
        uint2 u2 = X2[(size_t)e2.x * 64 + lane];
        uint2 u3 = X2[(size_t)e3.x * 64 + lane];
        uint2 u4 = X2[(size_t)e4.x * 64 + lane];
        uint2 u5 = X2[(size_t)e5.x * 64 + lane];
        uint2 u6 = X2[(size_t)e6.x * 64 + lane];
        uint2 u7 = X2[(size_t)e7.x * 64 + lane];
        float t0 = __int_as_float(e0.y), t1 = __int_as_float(e1.y);
        float t2 = __int_as_float(e2.y), t3 = __int_as_float(e3.y);
        float t4 = __int_as_float(e4.y), t5 = __int_as_float(e5.y);
        float t6 = __int_as_float(e6.y), t7 = __int_as_float(e7.y);
        ax = fmaf(t0, bf_lo(u0.x), ax); ay = fmaf(t0, bf_hi(u0.x), ay);
        az = fmaf(t0, bf_lo(u0.y), az); aw = fmaf(t0, bf_hi(u0.y), aw);
        ax = fmaf(t1, bf_lo(u1.x), ax); ay = fmaf(t1, bf_hi(u1.x), ay);
        az = fmaf(t1, bf_lo(u1.y), az); aw = fmaf(t1, bf_hi(u1.y), aw);
        ax = fmaf(t2, bf_lo(u2.x), ax); ay = fmaf(t2, bf_hi(u2.x), ay);
        az = fmaf(t2, bf_lo(u2.y), az); aw = fmaf(t2, bf_hi(u2.y), aw);
        ax = fmaf(t3, bf_lo(u3.x), ax); ay = fmaf(t3, bf_hi(u3.x), ay);
        az = fmaf(t3, bf_lo(u3.y), az); aw = fmaf(t3, bf_hi(u3.y), aw);
        ax = fmaf(t4, bf_lo(u4.x), ax); ay = fmaf(t4, bf_hi(u4.x), ay);
        az = fmaf(t4, bf_lo(u4.y), az); aw = fmaf(t4, bf_hi(u4.y), aw);
        ax = fmaf(t5, bf_lo(u5.x), ax); ay = fmaf(t5, bf_hi(u5.x), ay);
        az = fmaf(t5, bf_lo(u5.y), az); aw = fmaf(t5, bf_hi(u5.y), aw);
        ax = fmaf(t6, bf_lo(u6.x), ax); ay = fmaf(t6, bf_hi(u6.x), ay);
        az = fmaf(t6, bf_lo(u6.y), az); aw = fmaf(t6, bf_hi(u6.y), aw);
        ax = fmaf(t7, bf_lo(u7.x), ax); ay = fmaf(t7, bf_hi(u7.x), ay);
        az = fmaf(t7, bf_lo(u7.y), az); aw = fmaf(t7, bf_hi(u7.y), aw);
    }
    for (; j < jend; ++j) {
        int2 e = edges2[j];
        float wt = __int_as_float(e.y);
        uint2 u = X2[(size_t)e.x * 64 + lane];
        ax = fmaf(wt, bf_lo(u.x), ax);
        ay = fmaf(wt, bf_hi(u.x), ay);
        az = fmaf(wt, bf_lo(u.y), az);
        aw = fmaf(wt, bf_hi(u.y), aw);
    }
    if (out_bf16) {
        uint lo = (uint)f2bf(ax) | ((uint)f2bf(ay) << 16);
        uint hi = (uint)f2bf(az) | ((uint)f2bf(aw) << 16);
        ((uint2*)Yb)[(size_t)node * 64 + lane] = make_uint2(lo, hi);
    } else {
        ((float4*)Yf)[(size_t)node * 64 + lane] = make_float4(ax, ay, az, aw);
    }
}

// ------------------------------- BatchNorm ---------------------------------
// Stage A over bf16 Yb: 256 blocks, 8 independent uint2 loads in flight,
// LDS reduce over 4 row-groups, private partial row (no atomics).
#define BN_RPB 196
__global__ void bn_stats_kernel(const ushort* __restrict__ Yb, float* __restrict__ partials) {
    __shared__ float4 redS[4][64];
    __shared__ float4 redQ[4][64];
    int c = threadIdx.x & 63, g = threadIdx.x >> 6;
    int r0 = blockIdx.x * BN_RPB;
    int rend = min(r0 + BN_RPB, NN);
    const uint2* Y2 = (const uint2*)Yb;
    float4 s = make_float4(0.f, 0.f, 0.f, 0.f);
    float4 q = make_float4(0.f, 0.f, 0.f, 0.f);
    int r = r0 + g;
    for (; r + 28 < rend; r += 32) {
        uint2 u0 = Y2[(size_t)(r +  0) * 64 + c];
        uint2 u1 = Y2[(size_t)(r +  4) * 64 + c];
        uint2 u2 = Y2[(size_t)(r +  8) * 64 + c];
        uint2 u3 = Y2[(size_t)(r + 12) * 64 + c];
        uint2 u4 = Y2[(size_t)(r + 16) * 64 + c];
        uint2 u5 = Y2[(size_t)(r + 20) * 64 + c];
        uint2 u6 = Y2[(size_t)(r + 24) * 64 + c];
        uint2 u7 = Y2[(size_t)(r + 28) * 64 + c];
        #pragma unroll
        for (int t = 0; t < 8; ++t) {
            uint2 u = (t == 0) ? u0 : (t == 1) ? u1 : (t == 2) ? u2 : (t == 3) ? u3
                    : (t == 4) ? u4 : (t == 5) ? u5 : (t == 6) ? u6 : u7;
            float vx = bf_lo(u.x), vy = bf_hi(u.x), vz = bf_lo(u.y), vw = bf_hi(u.y);
            s.x += vx; s.y += vy; s.z += vz; s.w += vw;
            q.x = fmaf(vx, vx, q.x); q.y = fmaf(vy, vy, q.y);
            q.z = fmaf(vz, vz, q.z); q.w = fmaf(vw, vw, q.w);
        }
    }
    for (; r < rend; r += 4) {
        uint2 u = Y2[(size_t)r * 64 + c];
        float vx = bf_lo(u.x), vy = bf_hi(u.x), vz = bf_lo(u.y), vw = bf_hi(u.y);
        s.x += vx; s.y += vy; s.z += vz; s.w += vw;
        q.x = fmaf(vx, vx, q.x); q.y = fmaf(vy, vy, q.y);
        q.z = fmaf(vz, vz, q.z); q.w = fmaf(vw, vw, q.w);
    }
    redS[g][c] = s; redQ[g][c] = q;
    __syncthreads();
    if (g == 0) {
        float4 s1 = redS[1][c], s2 = redS[2][c], s3 = redS[3][c];
        float4 q1 = redQ[1][c], q2 = redQ[2][c], q3 = redQ[3][c];
        s.x += s1.x + s2.x + s3.x; s.y += s1.y + s2.y + s3.y;
        s.z += s1.z + s2.z + s3.z; s.w += s1.w + s2.w + s3.w;
        q.x += q1.x + q2.x + q3.x; q.y += q1.y + q2.y + q3.y;
        q.z += q1.z + q2.z + q3.z; q.w += q1.w + q2.w + q3.w;
        float* P = partials + (size_t)blockIdx.x * 512;
        *(float4*)&P[c * 4] = s;
        *(float4*)&P[256 + c * 4] = q;
    }
}

// Stage B + finalize: reduce 256 partial rows, emit scale/shift.
__global__ void bn_finalize_kernel(const float* __restrict__ partials,
                                   const float* __restrict__ g,
                                   const float* __restrict__ be,
                                   float* __restrict__ scsh) {
    __shared__ float rs[8][32], rq[8][32];
    int cl = threadIdx.x & 31, gr = threadIdx.x >> 5;
    int col = blockIdx.x * 32 + cl;
    float s = 0.f, q = 0.f;
    #pragma unroll 4
    for (int r = gr; r < 256; r += 8) {
        s += partials[(size_t)r * 512 + col];
        q += partials[(size_t)r * 512 + 256 + col];
    }
    rs[gr][cl] = s; rq[gr][cl] = q;
    __syncthreads();
    if (gr == 0) {
        #pragma unroll
        for (int i = 1; i < 8; ++i) { s += rs[i][cl]; q += rq[i][cl]; }
        const float invN = 1.0f / (float)NN;
        float m = s * invN;
        float var = fmaf(-m, m, q * invN);
        float sc = rsqrtf(var + 1e-5f) * g[col];
        scsh[col] = sc;
        scsh[256 + col] = fmaf(-m, sc, be[col]);
    }
}

// ---------------------------------------------------------------------------

extern "C" void kernel_launch(void* const* d_in, const int* in_sizes, int n_in,
                              void* d_out, int out_size, void* d_ws, size_t ws_size,
                              hipStream_t stream) {
    const float* h   = (const float*)d_in[0];
    const int*   ei  = (const int*)d_in[1];
    const float* ew  = (const float*)d_in[2];
    const float* W1  = (const float*)d_in[3];
    const float* b1  = (const float*)d_in[4];
    const float* g1  = (const float*)d_in[5];
    const float* be1 = (const float*)d_in[6];
    const float* Wm  = (const float*)d_in[7];
    const float* bm  = (const float*)d_in[8];
    const float* gm  = (const float*)d_in[9];
    const float* bem = (const float*)d_in[10];
    const float* Wl  = (const float*)d_in[11];
    const float* bl  = (const float*)d_in[12];

    const int* src = ei;
    const int* dst = ei + NE;

    char* ws = (char*)d_ws;
    size_t off = 0;
    auto alloc = [&](size_t bytes) { size_t o = off; off = (off + bytes + 255) & ~(size_t)255; return o; };
    ushort* Xb      = (ushort*)(ws + alloc((size_t)NN * DD * 2));
    ushort* Yb      = (ushort*)(ws + alloc((size_t)NN * DD * 2));
    ushort* Bt      = (ushort*)(ws + alloc((size_t)7 * DD * DD * 2));
    unsigned long long* cells = (unsigned long long*)(ws + alloc((size_t)NN * 8));
    float*  dinv    = (float*) (ws + alloc((size_t)NN * 4));
    float*  partials= (float*) (ws + alloc((size_t)256 * 512 * 4));
    float*  scsh    = (float*) (ws + alloc(512 * 4));
    int*    rowptr  = (int*)   (ws + alloc((size_t)(NN + 1) * 4));
    int*    cnt     = (int*)   (ws + alloc((size_t)NN * 4));
    int*    rank    = (int*)   (ws + alloc((size_t)NE * 4));
    int2*   edges2  = (int2*)  (ws + alloc((size_t)NE * 8));
    (void)ws_size;

    float* OUT = (float*)d_out;

    const int gN = (NN + 255) / 256;
    const int gE = (NE + 255) / 256;

    // --- gcn_norm + CSR build ---
    hipMemsetAsync(cells, 0, (size_t)NN * 8, stream);
    edge_stat_kernel<<<gE, 256, 0, stream>>>(dst, ew, cells, rank);
    deg_finish_kernel<<<gN, 256, 0, stream>>>(cells, cnt, dinv);
    scan_kernel<<<1, 1024, 0, stream>>>(cnt, rowptr, NN);
    fill_kernel<<<gE, 256, 0, stream>>>(src, dst, ew, dinv, rank, rowptr, edges2);

    // --- weights -> bf16 transposed ---
    wcvt_kernel<<<(7 * 65536 + 255) / 256, 256, 0, stream>>>(Wm, Wl, Bt);

    // --- layer 0 GEMM ---
    gemm0_kernel<<<NN, 256, 0, stream>>>(h, W1, Xb);

    // --- 8 layers ---
    for (int l = 0; l < 8; ++l) {
        const float* b_l = (l == 0) ? b1 : (l <= 6 ? bm + (l - 1) * 256 : bl);
        if (l >= 1) {
            const ushort* Btl = Bt + (size_t)(l - 1) * DD * DD;
            dim3 grid(2, (NN + 127) / 128);
            gemm_bn_kernel<<<grid, 256, 0, stream>>>(Yb, Btl, scsh, Xb, NN);
        }
        agg_kernel<<<(NN + 3) / 4, 256, 0, stream>>>(
            Xb, Yb, OUT, rowptr, edges2, dinv, b_l, (l < 7) ? 1 : 0);
        if (l < 7) {
            const float* g_l  = (l == 0) ? g1 : gm + (l - 1) * 256;
            const float* be_l = (l == 0) ? be1 : bem + (l - 1) * 256;
            bn_stats_kernel<<<256, 256, 0, stream>>>(Yb, partials);
            bn_finalize_kernel<<<8, 256, 0, stream>>>(partials, g_l, be_l, scsh);
        }
    }
}